// Round 9
// baseline (333.088 us; speedup 1.0000x reference)
//
#include <hip/hip_runtime.h>
#include <hip/hip_fp16.h>
#include <math.h>
#include <limits.h>

#define HH 8
#define CC 32
#define NEG 0.2f

struct __align__(8) half4 { __half2 a, b; };

__device__ __forceinline__ void edge_sd(const int* __restrict__ ei, int e, int E, int& s, int& d){
  if(e < E){ s = ei[e]; d = ei[E+e]; } else { s = e-E; d = s; }
}

// ------------------- CSR preprocessing (graph shared by both layers) -------------------

__global__ void k_zero(int* __restrict__ p, int n){
  int i = blockIdx.x*blockDim.x + threadIdx.x;
  if(i < n) p[i] = 0;
}

__global__ void k_count(const int* __restrict__ ei, int E, int ET, int* __restrict__ cnt){
  int e = blockIdx.x*blockDim.x + threadIdx.x;
  if(e >= ET) return;
  int d = (e < E) ? ei[E+e] : e-E;
  atomicAdd(&cnt[d], 1);
}

__global__ __launch_bounds__(256) void k_scan_block(const int* __restrict__ cnt,
                                                    int* __restrict__ off,
                                                    int* __restrict__ bsum, int N){
  int i = blockIdx.x*256 + threadIdx.x;
  int v = (i < N) ? cnt[i] : 0;
  int lane = threadIdx.x & 63;
  int incl = v;
  #pragma unroll
  for(int o=1;o<64;o<<=1){ int u = __shfl_up(incl,o); if(lane>=o) incl += u; }
  __shared__ int wsum[4];
  if(lane==63) wsum[threadIdx.x>>6] = incl;
  __syncthreads();
  int w = threadIdx.x>>6, wadd = 0;
  #pragma unroll
  for(int k=0;k<4;k++) if(k<w) wadd += wsum[k];
  if(i < N) off[i] = wadd + incl - v;
  if(threadIdx.x==255) bsum[blockIdx.x] = wadd + incl;
}

__global__ __launch_bounds__(256) void k_scan_bsum(int* __restrict__ bsum, int nb,
                                                   int* __restrict__ offN){
  int t = threadIdx.x;
  int v = (t < nb) ? bsum[t] : 0;
  int lane = t & 63;
  int incl = v;
  #pragma unroll
  for(int o=1;o<64;o<<=1){ int u = __shfl_up(incl,o); if(lane>=o) incl += u; }
  __shared__ int wsum[4];
  if(lane==63) wsum[t>>6] = incl;
  __syncthreads();
  int w = t>>6, wadd = 0;
  #pragma unroll
  for(int k=0;k<4;k++) if(k<w) wadd += wsum[k];
  if(t < nb) bsum[t] = wadd + incl - v;
  if(t == 255) *offN = wadd + incl;
}

__global__ void k_scan_add(int* __restrict__ off, const int* __restrict__ bsum,
                           int* __restrict__ cur, int N){
  int i = blockIdx.x*256 + threadIdx.x;
  if(i < N){ int v = off[i] + bsum[blockIdx.x]; off[i] = v; cur[i] = v; }
}

// scatter src node id AND its vocab id (for layer 1's vocab-space tables)
__global__ void k_scatter(const int* __restrict__ ei, int E, int ET,
                          const int* __restrict__ x,
                          int* __restrict__ cur, int* __restrict__ csr_src,
                          int* __restrict__ csr_xv){
  int e = blockIdx.x*blockDim.x + threadIdx.x;
  if(e >= ET) return;
  int s,d; edge_sd(ei,e,E,s,d);
  int pos = atomicAdd(&cur[d], 1);
  csr_src[pos] = s;
  csr_xv[pos]  = x[s];
}

// ws_s[k,h] = sum_c W2[k, h*32+c] * att_s2[h,c]   (and ws_d) — 1 block, 256 threads
__global__ __launch_bounds__(256) void k_ws(const float* __restrict__ W2,
                                            const float* __restrict__ att_s2,
                                            const float* __restrict__ att_d2,
                                            float* __restrict__ ws_s, float* __restrict__ ws_d){
  int k = threadIdx.x >> 3, h = threadIdx.x & 7;
  float ss = 0.f, dd = 0.f;
  for(int c=0;c<CC;c++){
    float w = W2[k*256 + h*CC + c];
    ss = fmaf(w, att_s2[h*CC+c], ss);
    dd = fmaf(w, att_d2[h*CC+c], dd);
  }
  ws_s[k*HH+h] = ss;
  ws_d[k*HH+h] = dd;
}

// ------------------- layer-1 vocab-space GEMM -------------------
// emb:[V,128] @ W1:[128,256] -> xl_v(fp16):[V,256], a_src_v/a_dst_v:[V,8]
__global__ __launch_bounds__(256,4) void k_gemm1(
    const float* __restrict__ X, const float* __restrict__ W,
    const float* __restrict__ att_s, const float* __restrict__ att_d,
    __half* __restrict__ xl, float* __restrict__ a_src, float* __restrict__ a_dst, int V){
  const int ROWS = 8, FIN = 128;
  __shared__ __align__(16) float xs[ROWS][FIN];
  int row0 = blockIdx.x*ROWS;
  int tid = threadIdx.x;
  for(int p = tid; p < ROWS*FIN; p += 256){
    int r = p/FIN, kk = p - r*FIN;
    int row = row0 + r;
    xs[r][kk] = (row < V) ? X[(size_t)row*FIN + kk] : 0.f;
  }
  __syncthreads();
  float acc[ROWS];
  #pragma unroll
  for(int r=0;r<ROWS;r++) acc[r]=0.f;
  for(int k=0;k<FIN;k++){
    float w = W[(size_t)k*256 + tid];
    #pragma unroll
    for(int r=0;r<ROWS;r++) acc[r] = fmaf(xs[r][k], w, acc[r]);
  }
  float as = att_s[tid], ad = att_d[tid];
  #pragma unroll
  for(int r=0;r<ROWS;r++){
    int n = row0+r;
    float v = acc[r];
    float ps = v*as, pd = v*ad;
    #pragma unroll
    for(int msk=16; msk>=1; msk>>=1){
      ps += __shfl_xor(ps, msk);
      pd += __shfl_xor(pd, msk);
    }
    if(n < V){
      xl[(size_t)n*256 + tid] = __float2half(v);
      if((tid&31)==0){
        int hh = tid>>5;
        a_src[n*HH+hh] = ps;
        a_dst[n*HH+hh] = pd;
      }
    }
  }
}

// ------------------- layer 1 fused: softmax + message agg + layer-2 score epilogue -------------------
// one wave per node; vocab-space gathers (xl_v 2.56MB, a_*_v 160KB: L2-resident)
__global__ __launch_bounds__(256) void k_fused1(
    const int* __restrict__ off, const int* __restrict__ csr_xv,
    const int* __restrict__ x,
    const float* __restrict__ a_src_v, const float* __restrict__ a_dst_v,
    const __half* __restrict__ xl_v, const float* __restrict__ bias,
    const float* __restrict__ ws_s, const float* __restrict__ ws_d,
    __half* __restrict__ h2h, float* __restrict__ a_src2, float* __restrict__ a_dst2, int N){
  int wid = (int)((blockIdx.x*(size_t)blockDim.x + threadIdx.x) >> 6);
  int lane = threadIdx.x & 63;
  if(wid >= N) return;
  const int start = off[wid], end = off[wid+1];
  const int t = lane >> 3, h = lane & 7;
  const int xv_n = x[wid];
  const float ad = a_dst_v[xv_n*HH + h];

  // pass 1: per-head max
  float m = -INFINITY;
  for(int j0 = start; j0 < end; j0 += 8){
    int jj = j0 + t;
    if(jj < end){
      float v = a_src_v[csr_xv[jj]*HH + h] + ad;
      v = v > 0.f ? v : NEG*v;
      m = fmaxf(m, v);
    }
  }
  #pragma unroll
  for(int msk=8; msk<64; msk<<=1) m = fmaxf(m, __shfl_xor(m, msk));

  // pass 2: exp once per (edge,head); 8 xl_v row gathers in flight
  const int h2 = lane >> 3, c0 = (lane & 7)*4;
  const __half* xp = xl_v + h2*CC + c0;
  float eesum = 0.f;
  float4 acc = make_float4(0.f,0.f,0.f,0.f);
  for(int j0 = start; j0 < end; j0 += 8){
    int jj = j0 + t;
    int sv = 0;
    float ee = 0.f;
    if(jj < end){
      sv = csr_xv[jj];
      float v = a_src_v[sv*HH + h] + ad;
      v = v > 0.f ? v : NEG*v;
      ee = expf(v - m);
      eesum += ee;
    }
    #pragma unroll
    for(int u=0; u<8; ++u){
      float a  = __shfl(ee, u*8 + h2);
      int   ss = __shfl(sv, u*8);
      half4 hv = *reinterpret_cast<const half4*>(xp + (size_t)ss*256);
      float2 f01 = __half22float2(hv.a), f23 = __half22float2(hv.b);
      acc.x = fmaf(a, f01.x, acc.x);
      acc.y = fmaf(a, f01.y, acc.y);
      acc.z = fmaf(a, f23.x, acc.z);
      acc.w = fmaf(a, f23.y, acc.w);
    }
  }
  #pragma unroll
  for(int msk=8; msk<64; msk<<=1) eesum += __shfl_xor(eesum, msk);
  float is2 = 0.125f / __shfl(eesum, h2);
  acc.x *= is2; acc.y *= is2; acc.z *= is2; acc.w *= is2;
  #pragma unroll
  for(int msk=8; msk<64; msk<<=1){
    acc.x += __shfl_xor(acc.x, msk);
    acc.y += __shfl_xor(acc.y, msk);
    acc.z += __shfl_xor(acc.z, msk);
    acc.w += __shfl_xor(acc.w, msk);
  }
  if(lane < 8){
    const float4 b = *reinterpret_cast<const float4*>(bias + c0);
    float4 o = make_float4(fmaxf(acc.x+b.x,0.f), fmaxf(acc.y+b.y,0.f),
                           fmaxf(acc.z+b.z,0.f), fmaxf(acc.w+b.w,0.f));
    half4 hv;
    hv.a = __floats2half2_rn(o.x, o.y);
    hv.b = __floats2half2_rn(o.z, o.w);
    *reinterpret_cast<half4*>(h2h + (size_t)wid*CC + c0) = hv;
    // layer-2 scores: a_src2[n,l] = sum_k h2[n,k]*ws_s[k,l]  (lane l = head)
    float ps = 0.f, pd = 0.f;
    #pragma unroll
    for(int g=0; g<8; ++g){
      float v0 = __shfl(o.x, g), v1 = __shfl(o.y, g), v2 = __shfl(o.z, g), v3 = __shfl(o.w, g);
      int kb = g*4;
      ps = fmaf(v0, ws_s[(kb+0)*HH+lane], ps);
      ps = fmaf(v1, ws_s[(kb+1)*HH+lane], ps);
      ps = fmaf(v2, ws_s[(kb+2)*HH+lane], ps);
      ps = fmaf(v3, ws_s[(kb+3)*HH+lane], ps);
      pd = fmaf(v0, ws_d[(kb+0)*HH+lane], pd);
      pd = fmaf(v1, ws_d[(kb+1)*HH+lane], pd);
      pd = fmaf(v2, ws_d[(kb+2)*HH+lane], pd);
      pd = fmaf(v3, ws_d[(kb+3)*HH+lane], pd);
    }
    a_src2[wid*HH + lane] = ps;
    a_dst2[wid*HH + lane] = pd;
  }
}

// ------------------- layer 2 fused: softmax + h2-space agg + per-node W2 transform -------------------
// agg[n,h,k] = sum_j alpha_jh * h2h[s_j,k]   (h2h 3.2MB: L2-resident)
// z[n,c] = sum_h sum_k agg[n,h,k]*W2[k,h*32+c] + b2[c]   (0.125 folded into normalization)
__global__ __launch_bounds__(256) void k_fused2(
    const int* __restrict__ off, const int* __restrict__ csr_src,
    const float* __restrict__ a_src2, const float* __restrict__ a_dst2,
    const __half* __restrict__ h2h, const float* __restrict__ W2,
    const float* __restrict__ b2, float* __restrict__ z, int N){
  __shared__ __align__(16) float aggl[4][256];
  int w = threadIdx.x >> 6;
  int wid = (int)(blockIdx.x*4 + w);
  int lane = threadIdx.x & 63;
  bool active = wid < N;
  int start = 0, end = 0;
  const int t = lane >> 3, h = lane & 7;
  float ad = 0.f;
  if(active){
    start = off[wid]; end = off[wid+1];
    ad = a_dst2[wid*HH + h];
  }

  float m = -INFINITY;
  for(int j0 = start; j0 < end; j0 += 8){
    int jj = j0 + t;
    if(jj < end){
      float v = a_src2[csr_src[jj]*HH + h] + ad;
      v = v > 0.f ? v : NEG*v;
      m = fmaxf(m, v);
    }
  }
  #pragma unroll
  for(int msk=8; msk<64; msk<<=1) m = fmaxf(m, __shfl_xor(m, msk));

  const int h2 = lane >> 3, k0 = (lane & 7)*4;
  const __half* hp = h2h + k0;
  float eesum = 0.f;
  float4 acc = make_float4(0.f,0.f,0.f,0.f);
  for(int j0 = start; j0 < end; j0 += 8){
    int jj = j0 + t;
    int s = 0;
    float ee = 0.f;
    if(jj < end){
      s = csr_src[jj];
      float v = a_src2[s*HH + h] + ad;
      v = v > 0.f ? v : NEG*v;
      ee = expf(v - m);
      eesum += ee;
    }
    #pragma unroll
    for(int u=0; u<8; ++u){
      float a  = __shfl(ee, u*8 + h2);
      int   ss = __shfl(s,  u*8);
      half4 hv = *reinterpret_cast<const half4*>(hp + (size_t)ss*CC);
      float2 f01 = __half22float2(hv.a), f23 = __half22float2(hv.b);
      acc.x = fmaf(a, f01.x, acc.x);
      acc.y = fmaf(a, f01.y, acc.y);
      acc.z = fmaf(a, f23.x, acc.z);
      acc.w = fmaf(a, f23.y, acc.w);
    }
  }
  #pragma unroll
  for(int msk=8; msk<64; msk<<=1) eesum += __shfl_xor(eesum, msk);
  float is2 = 0.125f / __shfl(eesum, h2);
  // agg[h2][k0..k0+3], alpha-normalized with head-mean folded
  *reinterpret_cast<float4*>(&aggl[w][h2*CC + k0]) =
      make_float4(acc.x*is2, acc.y*is2, acc.z*is2, acc.w*is2);
  __syncthreads();

  // transform: lane = (part = lane>>5, ch = lane&31); heads part*4..part*4+3
  const int ch = lane & 31, part = lane >> 5;
  float p = 0.f;
  #pragma unroll
  for(int hh = 0; hh < 4; ++hh){
    int hq = part*4 + hh;
    const float* wcol = W2 + hq*CC + ch;
    const float* arow = &aggl[w][hq*CC];
    #pragma unroll 8
    for(int k=0;k<CC;k++) p = fmaf(arow[k], wcol[(size_t)k*256], p);
  }
  p += __shfl_xor(p, 32);
  if(active && part==0) z[(size_t)wid*CC + ch] = p + b2[ch];
}

__global__ void k_decode(const int* __restrict__ eli, int EL,
                         const float* __restrict__ z, float* __restrict__ out){
  int e = blockIdx.x*blockDim.x + threadIdx.x;
  if(e >= EL) return;
  const float4* za = reinterpret_cast<const float4*>(z + (size_t)eli[e]*CC);
  const float4* zb = reinterpret_cast<const float4*>(z + (size_t)eli[EL+e]*CC);
  float s = 0.f;
  #pragma unroll
  for(int j=0;j<8;j++){
    float4 u = za[j], v = zb[j];
    s += u.x*v.x + u.y*v.y + u.z*v.z + u.w*v.w;
  }
  out[e] = s;
}

extern "C" void kernel_launch(void* const* d_in, const int* in_sizes, int n_in,
                              void* d_out, int out_size, void* d_ws, size_t ws_size,
                              hipStream_t stream){
  const int*   x   = (const int*)d_in[0];
  const int*   ei  = (const int*)d_in[1];
  const int*   eli = (const int*)d_in[2];
  const float* emb = (const float*)d_in[3];
  const float* W1  = (const float*)d_in[4];
  const float* as1 = (const float*)d_in[5];
  const float* ad1 = (const float*)d_in[6];
  const float* b1  = (const float*)d_in[7];
  const float* W2  = (const float*)d_in[8];
  const float* as2 = (const float*)d_in[9];
  const float* ad2 = (const float*)d_in[10];
  const float* b2  = (const float*)d_in[11];

  const int N  = in_sizes[0];
  const int V  = in_sizes[3]/128;   // 5000
  const int E  = in_sizes[1]/2;
  const int EL = in_sizes[2]/2;
  const int ET = E + N;             // edges + self-loops

  // ---- workspace layout (16B-aligned regions) ----
  __half* xl_v = (__half*)d_ws;                         // V*256 halves
  __half* h2h  = xl_v + (size_t)V*256;                  // N*32 halves
  float* a_src_v = (float*)(h2h + (size_t)N*CC);        // V*8
  float* a_dst_v = a_src_v + (size_t)V*HH;              // V*8
  float* a_src2  = a_dst_v + (size_t)V*HH;              // N*8
  float* a_dst2  = a_src2 + (size_t)N*HH;               // N*8
  float* z       = a_dst2 + (size_t)N*HH;               // N*32
  float* ws_s    = z + (size_t)N*CC;                    // 256
  float* ws_d    = ws_s + 256;                          // 256
  int*   cnt   = (int*)(ws_d + 256);                    // N
  int*   off   = cnt + N;                               // N+1
  int*   cur   = off + N + 1;                           // N
  int*   bsum  = cur + N;                               // cdiv(N,256)
  int*   csr   = bsum + ((N+255)/256);                  // ET
  int*   csr_xv= csr + ET;                              // ET

  dim3 blk(256);
  auto cdiv = [](long long a, long long b){ return (unsigned)((a+b-1)/b); };
  const int nb = (int)cdiv(N,256);

  // ---- CSR build ----
  k_zero<<<cdiv(N,256), blk, 0, stream>>>(cnt, N);
  k_count<<<cdiv(ET,256), blk, 0, stream>>>(ei, E, ET, cnt);
  k_scan_block<<<nb, blk, 0, stream>>>(cnt, off, bsum, N);
  k_scan_bsum<<<1, blk, 0, stream>>>(bsum, nb, off + N);
  k_scan_add<<<nb, blk, 0, stream>>>(off, bsum, cur, N);
  k_scatter<<<cdiv(ET,256), blk, 0, stream>>>(ei, E, ET, x, cur, csr, csr_xv);

  // ---- small precomputes ----
  k_ws<<<1, blk, 0, stream>>>(W2, as2, ad2, ws_s, ws_d);

  // ---- layer 1 in vocab space ----
  k_gemm1<<<cdiv(V,8), blk, 0, stream>>>(emb, W1, as1, ad1, xl_v, a_src_v, a_dst_v, V);
  k_fused1<<<cdiv((long long)N*64,256), blk, 0, stream>>>(off, csr_xv, x, a_src_v, a_dst_v,
                                                          xl_v, b1, ws_s, ws_d,
                                                          h2h, a_src2, a_dst2, N);

  // ---- layer 2 (agg in h2 space + per-node transform) ----
  k_fused2<<<cdiv((long long)N*64,256), blk, 0, stream>>>(off, csr, a_src2, a_dst2,
                                                          h2h, W2, b2, z, N);

  // ---- decode ----
  k_decode<<<cdiv(EL,256), blk, 0, stream>>>(eli, EL, z, (float*)d_out);
}

// Round 10
// 325.492 us; speedup vs baseline: 1.0233x; 1.0233x over previous
//
#include <hip/hip_runtime.h>
#include <hip/hip_fp16.h>
#include <math.h>
#include <limits.h>

#define HH 8
#define CC 32
#define NEG 0.2f

struct __align__(8) half4 { __half2 a, b; };

__device__ __forceinline__ void edge_sd(const int* __restrict__ ei, int e, int E, int& s, int& d){
  if(e < E){ s = ei[e]; d = ei[E+e]; } else { s = e-E; d = s; }
}

// ------------------- CSR preprocessing (graph shared by both layers) -------------------

__global__ void k_zero(int* __restrict__ p, int n){
  int i = blockIdx.x*blockDim.x + threadIdx.x;
  if(i < n) p[i] = 0;
}

__global__ void k_count(const int* __restrict__ ei, int E, int ET, int* __restrict__ cnt){
  int e = blockIdx.x*blockDim.x + threadIdx.x;
  if(e >= ET) return;
  int d = (e < E) ? ei[E+e] : e-E;
  atomicAdd(&cnt[d], 1);
}

__global__ __launch_bounds__(256) void k_scan_block(const int* __restrict__ cnt,
                                                    int* __restrict__ off,
                                                    int* __restrict__ bsum, int N){
  int i = blockIdx.x*256 + threadIdx.x;
  int v = (i < N) ? cnt[i] : 0;
  int lane = threadIdx.x & 63;
  int incl = v;
  #pragma unroll
  for(int o=1;o<64;o<<=1){ int u = __shfl_up(incl,o); if(lane>=o) incl += u; }
  __shared__ int wsum[4];
  if(lane==63) wsum[threadIdx.x>>6] = incl;
  __syncthreads();
  int w = threadIdx.x>>6, wadd = 0;
  #pragma unroll
  for(int k=0;k<4;k++) if(k<w) wadd += wsum[k];
  if(i < N) off[i] = wadd + incl - v;
  if(threadIdx.x==255) bsum[blockIdx.x] = wadd + incl;
}

__global__ __launch_bounds__(256) void k_scan_bsum(int* __restrict__ bsum, int nb,
                                                   int* __restrict__ offN){
  int t = threadIdx.x;
  int v = (t < nb) ? bsum[t] : 0;
  int lane = t & 63;
  int incl = v;
  #pragma unroll
  for(int o=1;o<64;o<<=1){ int u = __shfl_up(incl,o); if(lane>=o) incl += u; }
  __shared__ int wsum[4];
  if(lane==63) wsum[t>>6] = incl;
  __syncthreads();
  int w = t>>6, wadd = 0;
  #pragma unroll
  for(int k=0;k<4;k++) if(k<w) wadd += wsum[k];
  if(t < nb) bsum[t] = wadd + incl - v;
  if(t == 255) *offN = wadd + incl;
}

__global__ void k_scan_add(int* __restrict__ off, const int* __restrict__ bsum,
                           int* __restrict__ cur, int N){
  int i = blockIdx.x*256 + threadIdx.x;
  if(i < N){ int v = off[i] + bsum[blockIdx.x]; off[i] = v; cur[i] = v; }
}

// scatter src node id AND its vocab id (for layer 1's vocab-space tables)
__global__ void k_scatter(const int* __restrict__ ei, int E, int ET,
                          const int* __restrict__ x,
                          int* __restrict__ cur, int* __restrict__ csr_src,
                          int* __restrict__ csr_xv){
  int e = blockIdx.x*blockDim.x + threadIdx.x;
  if(e >= ET) return;
  int s,d; edge_sd(ei,e,E,s,d);
  int pos = atomicAdd(&cur[d], 1);
  csr_src[pos] = s;
  csr_xv[pos]  = x[s];
}

// ws_s[k,h] = sum_c W2[k, h*32+c] * att_s2[h,c]   (and ws_d) — 1 block, 256 threads
__global__ __launch_bounds__(256) void k_ws(const float* __restrict__ W2,
                                            const float* __restrict__ att_s2,
                                            const float* __restrict__ att_d2,
                                            float* __restrict__ ws_s, float* __restrict__ ws_d){
  int k = threadIdx.x >> 3, h = threadIdx.x & 7;
  float ss = 0.f, dd = 0.f;
  for(int c=0;c<CC;c++){
    float w = W2[k*256 + h*CC + c];
    ss = fmaf(w, att_s2[h*CC+c], ss);
    dd = fmaf(w, att_d2[h*CC+c], dd);
  }
  ws_s[k*HH+h] = ss;
  ws_d[k*HH+h] = dd;
}

// ------------------- layer-1 vocab-space GEMM -------------------
// emb:[V,128] @ W1:[128,256] -> xl_v(fp16):[V,256], a_src_v/a_dst_v:[V,8]
__global__ __launch_bounds__(256,4) void k_gemm1(
    const float* __restrict__ X, const float* __restrict__ W,
    const float* __restrict__ att_s, const float* __restrict__ att_d,
    __half* __restrict__ xl, float* __restrict__ a_src, float* __restrict__ a_dst, int V){
  const int ROWS = 8, FIN = 128;
  __shared__ __align__(16) float xs[ROWS][FIN];
  int row0 = blockIdx.x*ROWS;
  int tid = threadIdx.x;
  for(int p = tid; p < ROWS*FIN; p += 256){
    int r = p/FIN, kk = p - r*FIN;
    int row = row0 + r;
    xs[r][kk] = (row < V) ? X[(size_t)row*FIN + kk] : 0.f;
  }
  __syncthreads();
  float acc[ROWS];
  #pragma unroll
  for(int r=0;r<ROWS;r++) acc[r]=0.f;
  for(int k=0;k<FIN;k++){
    float w = W[(size_t)k*256 + tid];
    #pragma unroll
    for(int r=0;r<ROWS;r++) acc[r] = fmaf(xs[r][k], w, acc[r]);
  }
  float as = att_s[tid], ad = att_d[tid];
  #pragma unroll
  for(int r=0;r<ROWS;r++){
    int n = row0+r;
    float v = acc[r];
    float ps = v*as, pd = v*ad;
    #pragma unroll
    for(int msk=16; msk>=1; msk>>=1){
      ps += __shfl_xor(ps, msk);
      pd += __shfl_xor(pd, msk);
    }
    if(n < V){
      xl[(size_t)n*256 + tid] = __float2half(v);
      if((tid&31)==0){
        int hh = tid>>5;
        a_src[n*HH+hh] = ps;
        a_dst[n*HH+hh] = pd;
      }
    }
  }
}

// ------------------- layer 1 fused: softmax + message agg + layer-2 score epilogue -------------------
// one wave per node; vocab-space gathers (xl_v 2.56MB, a_*_v 160KB: L2-resident)
__global__ __launch_bounds__(256) void k_fused1(
    const int* __restrict__ off, const int* __restrict__ csr_xv,
    const int* __restrict__ x,
    const float* __restrict__ a_src_v, const float* __restrict__ a_dst_v,
    const __half* __restrict__ xl_v, const float* __restrict__ bias,
    const float* __restrict__ ws_s, const float* __restrict__ ws_d,
    __half* __restrict__ h2h, float* __restrict__ a_src2, float* __restrict__ a_dst2, int N){
  int wid = (int)((blockIdx.x*(size_t)blockDim.x + threadIdx.x) >> 6);
  int lane = threadIdx.x & 63;
  if(wid >= N) return;
  const int start = off[wid], end = off[wid+1];
  const int t = lane >> 3, h = lane & 7;
  const int xv_n = x[wid];
  const float ad = a_dst_v[xv_n*HH + h];

  // pass 1: per-head max
  float m = -INFINITY;
  for(int j0 = start; j0 < end; j0 += 8){
    int jj = j0 + t;
    if(jj < end){
      float v = a_src_v[csr_xv[jj]*HH + h] + ad;
      v = v > 0.f ? v : NEG*v;
      m = fmaxf(m, v);
    }
  }
  #pragma unroll
  for(int msk=8; msk<64; msk<<=1) m = fmaxf(m, __shfl_xor(m, msk));

  // pass 2: exp once per (edge,head); 8 xl_v row gathers in flight
  const int h2 = lane >> 3, c0 = (lane & 7)*4;
  const __half* xp = xl_v + h2*CC + c0;
  float eesum = 0.f;
  float4 acc = make_float4(0.f,0.f,0.f,0.f);
  for(int j0 = start; j0 < end; j0 += 8){
    int jj = j0 + t;
    int sv = 0;
    float ee = 0.f;
    if(jj < end){
      sv = csr_xv[jj];
      float v = a_src_v[sv*HH + h] + ad;
      v = v > 0.f ? v : NEG*v;
      ee = expf(v - m);
      eesum += ee;
    }
    #pragma unroll
    for(int u=0; u<8; ++u){
      float a  = __shfl(ee, u*8 + h2);
      int   ss = __shfl(sv, u*8);
      half4 hv = *reinterpret_cast<const half4*>(xp + (size_t)ss*256);
      float2 f01 = __half22float2(hv.a), f23 = __half22float2(hv.b);
      acc.x = fmaf(a, f01.x, acc.x);
      acc.y = fmaf(a, f01.y, acc.y);
      acc.z = fmaf(a, f23.x, acc.z);
      acc.w = fmaf(a, f23.y, acc.w);
    }
  }
  #pragma unroll
  for(int msk=8; msk<64; msk<<=1) eesum += __shfl_xor(eesum, msk);
  float is2 = 0.125f / __shfl(eesum, h2);
  acc.x *= is2; acc.y *= is2; acc.z *= is2; acc.w *= is2;
  #pragma unroll
  for(int msk=8; msk<64; msk<<=1){
    acc.x += __shfl_xor(acc.x, msk);
    acc.y += __shfl_xor(acc.y, msk);
    acc.z += __shfl_xor(acc.z, msk);
    acc.w += __shfl_xor(acc.w, msk);
  }
  if(lane < 8){
    const float4 b = *reinterpret_cast<const float4*>(bias + c0);
    float4 o = make_float4(fmaxf(acc.x+b.x,0.f), fmaxf(acc.y+b.y,0.f),
                           fmaxf(acc.z+b.z,0.f), fmaxf(acc.w+b.w,0.f));
    half4 hv;
    hv.a = __floats2half2_rn(o.x, o.y);
    hv.b = __floats2half2_rn(o.z, o.w);
    *reinterpret_cast<half4*>(h2h + (size_t)wid*CC + c0) = hv;
    // layer-2 scores: a_src2[n,l] = sum_k h2[n,k]*ws_s[k,l]  (lane l = head)
    float ps = 0.f, pd = 0.f;
    #pragma unroll
    for(int g=0; g<8; ++g){
      float v0 = __shfl(o.x, g), v1 = __shfl(o.y, g), v2 = __shfl(o.z, g), v3 = __shfl(o.w, g);
      int kb = g*4;
      ps = fmaf(v0, ws_s[(kb+0)*HH+lane], ps);
      ps = fmaf(v1, ws_s[(kb+1)*HH+lane], ps);
      ps = fmaf(v2, ws_s[(kb+2)*HH+lane], ps);
      ps = fmaf(v3, ws_s[(kb+3)*HH+lane], ps);
      pd = fmaf(v0, ws_d[(kb+0)*HH+lane], pd);
      pd = fmaf(v1, ws_d[(kb+1)*HH+lane], pd);
      pd = fmaf(v2, ws_d[(kb+2)*HH+lane], pd);
      pd = fmaf(v3, ws_d[(kb+3)*HH+lane], pd);
    }
    a_src2[wid*HH + lane] = ps;
    a_dst2[wid*HH + lane] = pd;
  }
}

// ------------------- layer 2 fused: softmax + h2-space agg + per-node W2 transform -------------------
// agg[n,h,k] = sum_j alpha_jh * h2h[s_j,k]   (h2h 3.2MB: L2-resident)
// z[n,c] = sum_h sum_k agg[n,h,k]*W2[k,h*32+c] + b2[c]   (0.125 folded into normalization)
__global__ __launch_bounds__(256) void k_fused2(
    const int* __restrict__ off, const int* __restrict__ csr_src,
    const float* __restrict__ a_src2, const float* __restrict__ a_dst2,
    const __half* __restrict__ h2h, const float* __restrict__ W2,
    const float* __restrict__ b2, float* __restrict__ z, int N){
  __shared__ __align__(16) float aggl[4][256];
  int w = threadIdx.x >> 6;
  int wid = (int)(blockIdx.x*4 + w);
  int lane = threadIdx.x & 63;
  bool active = wid < N;
  int start = 0, end = 0;
  const int t = lane >> 3, h = lane & 7;
  float ad = 0.f;
  if(active){
    start = off[wid]; end = off[wid+1];
    ad = a_dst2[wid*HH + h];
  }

  float m = -INFINITY;
  for(int j0 = start; j0 < end; j0 += 8){
    int jj = j0 + t;
    if(jj < end){
      float v = a_src2[csr_src[jj]*HH + h] + ad;
      v = v > 0.f ? v : NEG*v;
      m = fmaxf(m, v);
    }
  }
  #pragma unroll
  for(int msk=8; msk<64; msk<<=1) m = fmaxf(m, __shfl_xor(m, msk));

  const int h2 = lane >> 3, k0 = (lane & 7)*4;
  const __half* hp = h2h + k0;
  float eesum = 0.f;
  float4 acc = make_float4(0.f,0.f,0.f,0.f);
  for(int j0 = start; j0 < end; j0 += 8){
    int jj = j0 + t;
    int s = 0;
    float ee = 0.f;
    if(jj < end){
      s = csr_src[jj];
      float v = a_src2[s*HH + h] + ad;
      v = v > 0.f ? v : NEG*v;
      ee = expf(v - m);
      eesum += ee;
    }
    #pragma unroll
    for(int u=0; u<8; ++u){
      float a  = __shfl(ee, u*8 + h2);
      int   ss = __shfl(s,  u*8);
      half4 hv = *reinterpret_cast<const half4*>(hp + (size_t)ss*CC);
      float2 f01 = __half22float2(hv.a), f23 = __half22float2(hv.b);
      acc.x = fmaf(a, f01.x, acc.x);
      acc.y = fmaf(a, f01.y, acc.y);
      acc.z = fmaf(a, f23.x, acc.z);
      acc.w = fmaf(a, f23.y, acc.w);
    }
  }
  #pragma unroll
  for(int msk=8; msk<64; msk<<=1) eesum += __shfl_xor(eesum, msk);
  float is2 = 0.125f / __shfl(eesum, h2);
  // agg[h2][k0..k0+3], alpha-normalized with head-mean folded
  *reinterpret_cast<float4*>(&aggl[w][h2*CC + k0]) =
      make_float4(acc.x*is2, acc.y*is2, acc.z*is2, acc.w*is2);
  __syncthreads();

  // transform: lane = (part = lane>>5, ch = lane&31); heads part*4..part*4+3
  const int ch = lane & 31, part = lane >> 5;
  float p = 0.f;
  #pragma unroll
  for(int hh = 0; hh < 4; ++hh){
    int hq = part*4 + hh;
    const float* wcol = W2 + hq*CC + ch;
    const float* arow = &aggl[w][hq*CC];
    #pragma unroll 8
    for(int k=0;k<CC;k++) p = fmaf(arow[k], wcol[(size_t)k*256], p);
  }
  p += __shfl_xor(p, 32);
  if(active && part==0) z[(size_t)wid*CC + ch] = p + b2[ch];
}

__global__ void k_decode(const int* __restrict__ eli, int EL,
                         const float* __restrict__ z, float* __restrict__ out){
  int e = blockIdx.x*blockDim.x + threadIdx.x;
  if(e >= EL) return;
  const float4* za = reinterpret_cast<const float4*>(z + (size_t)eli[e]*CC);
  const float4* zb = reinterpret_cast<const float4*>(z + (size_t)eli[EL+e]*CC);
  float s = 0.f;
  #pragma unroll
  for(int j=0;j<8;j++){
    float4 u = za[j], v = zb[j];
    s += u.x*v.x + u.y*v.y + u.z*v.z + u.w*v.w;
  }
  out[e] = s;
}

extern "C" void kernel_launch(void* const* d_in, const int* in_sizes, int n_in,
                              void* d_out, int out_size, void* d_ws, size_t ws_size,
                              hipStream_t stream){
  const int*   x   = (const int*)d_in[0];
  const int*   ei  = (const int*)d_in[1];
  const int*   eli = (const int*)d_in[2];
  const float* emb = (const float*)d_in[3];
  const float* W1  = (const float*)d_in[4];
  const float* as1 = (const float*)d_in[5];
  const float* ad1 = (const float*)d_in[6];
  const float* b1  = (const float*)d_in[7];
  const float* W2  = (const float*)d_in[8];
  const float* as2 = (const float*)d_in[9];
  const float* ad2 = (const float*)d_in[10];
  const float* b2  = (const float*)d_in[11];

  const int N  = in_sizes[0];
  const int V  = in_sizes[3]/128;   // 5000
  const int E  = in_sizes[1]/2;
  const int EL = in_sizes[2]/2;
  const int ET = E + N;             // edges + self-loops

  // ---- workspace layout (16B-aligned regions) ----
  __half* xl_v = (__half*)d_ws;                         // V*256 halves
  __half* h2h  = xl_v + (size_t)V*256;                  // N*32 halves
  float* a_src_v = (float*)(h2h + (size_t)N*CC);        // V*8
  float* a_dst_v = a_src_v + (size_t)V*HH;              // V*8
  float* a_src2  = a_dst_v + (size_t)V*HH;              // N*8
  float* a_dst2  = a_src2 + (size_t)N*HH;               // N*8
  float* z       = a_dst2 + (size_t)N*HH;               // N*32
  float* ws_s    = z + (size_t)N*CC;                    // 256
  float* ws_d    = ws_s + 256;                          // 256
  int*   cnt   = (int*)(ws_d + 256);                    // N
  int*   off   = cnt + N;                               // N+1
  int*   cur   = off + N + 1;                           // N
  int*   bsum  = cur + N;                               // cdiv(N,256)
  int*   csr   = bsum + ((N+255)/256);                  // ET
  int*   csr_xv= csr + ET;                              // ET

  dim3 blk(256);
  auto cdiv = [](long long a, long long b){ return (unsigned)((a+b-1)/b); };
  const int nb = (int)cdiv(N,256);

  // ---- CSR build ----
  k_zero<<<cdiv(N,256), blk, 0, stream>>>(cnt, N);
  k_count<<<cdiv(ET,256), blk, 0, stream>>>(ei, E, ET, cnt);
  k_scan_block<<<nb, blk, 0, stream>>>(cnt, off, bsum, N);
  k_scan_bsum<<<1, blk, 0, stream>>>(bsum, nb, off + N);
  k_scan_add<<<nb, blk, 0, stream>>>(off, bsum, cur, N);
  k_scatter<<<cdiv(ET,256), blk, 0, stream>>>(ei, E, ET, x, cur, csr, csr_xv);

  // ---- small precomputes ----
  k_ws<<<1, blk, 0, stream>>>(W2, as2, ad2, ws_s, ws_d);

  // ---- layer 1 in vocab space ----
  k_gemm1<<<cdiv(V,8), blk, 0, stream>>>(emb, W1, as1, ad1, xl_v, a_src_v, a_dst_v, V);
  k_fused1<<<cdiv((long long)N*64,256), blk, 0, stream>>>(off, csr_xv, x, a_src_v, a_dst_v,
                                                          xl_v, b1, ws_s, ws_d,
                                                          h2h, a_src2, a_dst2, N);

  // ---- layer 2 (agg in h2 space + per-node transform) ----
  k_fused2<<<cdiv((long long)N*64,256), blk, 0, stream>>>(off, csr, a_src2, a_dst2,
                                                          h2h, W2, b2, z, N);

  // ---- decode ----
  k_decode<<<cdiv(EL,256), blk, 0, stream>>>(eli, EL, z, (float*)d_out);
}